// Round 4
// baseline (597.669 us; speedup 1.0000x reference)
//
#include <hip/hip_runtime.h>
#include <hip/hip_bf16.h>
#include <stdint.h>

// Problem: LuongConcatAttention (additive attention), fp32 inputs.
//   dec (32,1024) f32; enc (32,2048,1024) f32; W_a (1024,2048) f32; v (1024) f32
//   out alpha (32,2048) f32 = softmax_s( sum_e tanh(decproj[b,e]+encproj[b,s,e]) * v[e] )
// Round 8: true deep pipeline. BM=256 BN=128 BK=64, 512 thr (2x4 waves).
// A triple-buffered LDS staged 2 tiles ahead (HBM-latency cover), B double-buffered
// staged 1 ahead (L2-resident). One counted vmcnt(4) per K-tile that retires exactly
// the next tile's stages while keeping A(t+2) in flight. Depth-1 dbuf (R6/R7) was
// neutral: lookahead ~1 phase < L3/HBM latency. decproj: read Wd once, not 32x.

typedef __bf16 bf16x8 __attribute__((ext_vector_type(8)));
typedef __bf16 bf16x2 __attribute__((ext_vector_type(2)));
typedef float floatx4 __attribute__((ext_vector_type(4)));
typedef unsigned short ushort_t;

#define M_TOT 65536
#define D_DIM 1024
#define WA_LD 2048
#define S_DIM 2048

#define A_TILE 16384   // 256 rows * 64 k elems
#define B_TILE 8192    // 128 rows * 64 k elems

#define VMCNT4 asm volatile("s_waitcnt vmcnt(4)" ::: "memory")
#define VMCNT0 asm volatile("s_waitcnt vmcnt(0)" ::: "memory")
#define LGKM0  asm volatile("s_waitcnt lgkmcnt(0)" ::: "memory")
#define BAR    __builtin_amdgcn_s_barrier()
#define SCHED0 __builtin_amdgcn_sched_barrier(0)

__device__ __forceinline__ unsigned int pack2(float a, float b) {
#if __has_builtin(__builtin_amdgcn_cvt_pk_bf16_f32)
    bf16x2 p = __builtin_amdgcn_cvt_pk_bf16_f32(a, b);
    return __builtin_bit_cast(unsigned int, p);
#else
    unsigned int ua = __float_as_uint(a), ub = __float_as_uint(b);
    ua += 0x7fffu + ((ua >> 16) & 1u);     // RNE (inputs finite)
    ub += 0x7fffu + ((ub >> 16) & 1u);
    return __builtin_amdgcn_perm(ub, ua, 0x07060302);  // {ub.hi16, ua.hi16}
#endif
}

// async global->LDS, 16B per lane; LDS dest = wave-uniform base + lane*16
__device__ __forceinline__ void gl16(const ushort_t* g, ushort_t* l) {
    __builtin_amdgcn_global_load_lds(
        (const __attribute__((address_space(1))) unsigned int*)g,
        (__attribute__((address_space(3))) unsigned int*)l,
        16, 0, 0);
}

// ---------------- kernel 0a: We (W_a[:,1024:]) -> bf16 [1024][1024] ----------------
__global__ __launch_bounds__(256) void convertW_kernel(
    const float* __restrict__ Wa, ushort_t* __restrict__ Web)
{
    const int e = blockIdx.x;
    const int k = threadIdx.x * 4;
    float4 wv = *(const float4*)(Wa + (size_t)e * WA_LD + D_DIM + k);
    uint2 pk = { pack2(wv.x, wv.y), pack2(wv.z, wv.w) };
    *(uint2*)(Web + (size_t)e * D_DIM + k) = pk;
}

// ---------------- kernel 0b: enc -> bf16, 67.1M elements, BW-bound ----------------
__global__ __launch_bounds__(256) void convert_enc_kernel(
    const float* __restrict__ in, ushort_t* __restrict__ out)
{
    size_t i = ((size_t)blockIdx.x * 256 + threadIdx.x) * 8;
    const size_t stride = (size_t)4096 * 256 * 8;
    for (int it = 0; it < 8; ++it, i += stride) {
        float4 a = *(const float4*)(in + i);
        float4 b = *(const float4*)(in + i + 4);
        uint4 pk = { pack2(a.x, a.y), pack2(a.z, a.w), pack2(b.x, b.y), pack2(b.z, b.w) };
        *(uint4*)(out + i) = pk;
    }
}

// ---------------- kernel 1: dec_proj[b][e] = sum_k dec[b,k] * W_a[e,k] ----------------
// Wd read ONCE (4 MB). dec (128 KB) cached in LDS. grid 256 blocks, wave -> e.
__global__ __launch_bounds__(256) void decproj_kernel(
    const float* __restrict__ dec,
    const float* __restrict__ Wa,
    float* __restrict__ dp)
{
    __shared__ float s_d[32 * 1024];    // 128 KB: all of dec
    const int tid  = threadIdx.x;
    const int wave = tid >> 6;
    const int lane = tid & 63;
    const int e    = blockIdx.x * 4 + wave;

    for (int idx = tid; idx < 8192; idx += 256)
        *(float4*)&s_d[idx * 4] = *(const float4*)&dec[idx * 4];
    __syncthreads();

    const float* wrow = Wa + (size_t)e * WA_LD;   // Wd = W_a[:, :1024]
    float4 wv[4];
    #pragma unroll
    for (int i = 0; i < 4; ++i)
        wv[i] = *(const float4*)(wrow + i * 256 + lane * 4);

    for (int b = 0; b < 32; ++b) {
        float sum = 0.f;
        #pragma unroll
        for (int i = 0; i < 4; ++i) {
            float4 d = *(const float4*)&s_d[b * 1024 + i * 256 + lane * 4];
            sum += wv[i].x * d.x + wv[i].y * d.y + wv[i].z * d.z + wv[i].w * d.w;
        }
        #pragma unroll
        for (int msk = 1; msk < 64; msk <<= 1)
            sum += __shfl_xor(sum, msk, 64);
        if (lane == 0)
            dp[b * 1024 + e] = sum;
    }
}

// ---------------- kernel 2: bf16 GEMM (enc @ We^T) + tanh + v-dot -> partial ----------
// BM=256 BN=128 BK=64, 512 thr. A 3-buf (stage t+2), B 2-buf (stage t+1).
// vmcnt(4) once per tile retires {A(t+1),B(t+1)}, keeps A(t+2) in flight.
__global__ __launch_bounds__(512) void gemm_bf16_kernel(
    const ushort_t* __restrict__ A,      // enc bf16 [65536][1024]
    const ushort_t* __restrict__ Bw,     // We  bf16 [1024][1024]
    const float* __restrict__ v,
    const float* __restrict__ dp,
    float* __restrict__ partial)         // [8][65536]
{
    __shared__ ushort_t Asm[3 * A_TILE];        // 96 KB
    __shared__ ushort_t Bsm[2 * B_TILE];        // 32 KB
    __shared__ float s_dec[128], s_v[128];
    __shared__ float s_sc[4][256];

    const int tid  = threadIdx.x;
    const int lane = tid & 63;
    const int w    = tid >> 6;    // 0..7
    const int wm   = w >> 2;      // 0..1  (M half)
    const int wn   = w & 3;       // 0..3  (N quarter)
    const int r16  = lane & 15;
    const int q    = lane >> 4;

    // XCD chunk swizzle: 2048 blocks, each XCD gets 32 consecutive m-panels w/ all 8 n.
    const int flat    = blockIdx.y * 8 + blockIdx.x;       // grid (8, 256)
    const int logical = (flat & 7) * 256 + (flat >> 3);
    const int n_block = logical & 7;
    const int m_block = logical >> 3;            // 0..255
    const int b_idx   = m_block >> 3;            // 2048/256 = 8 m-tiles per batch row
    const int m_base  = m_block * 256;
    const int n_base  = n_block * 128;

    if (tid < 128) {
        s_dec[tid] = dp[b_idx * 1024 + n_base + tid];
        s_v[tid]   = v[n_base + tid];
    }
    __syncthreads();   // drain before pipelined staging begins

    // ---- staging addressing (both-sides swizzle: slot ^= row&7) ----
    const int grow = tid >> 3;                               // 0..63 rows per gl16
    const int gcol = (((tid & 7) ^ (grow & 7)) << 3);        // swizzled 8-elem slot

    auto stageA = [&](int h, int tsrc) {   // half h (128 rows), tile tsrc -> buf tsrc%3
        ushort_t* dst = &Asm[(tsrc % 3) * A_TILE + h * 8192 + w * 512];
        const ushort_t* src = A + (size_t)(m_base + h * 128 + grow) * D_DIM + tsrc * 64 + gcol;
        gl16(src, dst);
        gl16(src + (size_t)64 * D_DIM, dst + 4096);
    };
    auto stageB = [&](int tsrc) {          // all 128 rows, tile tsrc -> buf tsrc%2
        ushort_t* dst = &Bsm[(tsrc & 1) * B_TILE + w * 512];
        const ushort_t* src = Bw + (size_t)(n_base + grow) * D_DIM + tsrc * 64 + gcol;
        gl16(src, dst);
        gl16(src + (size_t)64 * D_DIM, dst + 4096);
    };

    // ---- fragment read offsets (elems). LDS rows 64 elems=128B; slot ^= row&7 ----
    int arow[8], brow[2];
    #pragma unroll
    for (int i = 0; i < 8; ++i) arow[i] = (wm * 128 + i * 16 + r16) * 64;
    #pragma unroll
    for (int j = 0; j < 2; ++j) brow[j] = (wn * 32 + j * 16 + r16) * 64;
    const int sl0 = ((q ^ (r16 & 7)) << 3);        // ks=0 slot
    const int sl1 = sl0 ^ 32;                      // ks=1 slot (+4 slots)

    floatx4 acc[8][2] = {};

    auto phase = [&](const ushort_t* At, const ushort_t* Bt, int slk) {
        bf16x8 af[8], bq[2];
        #pragma unroll
        for (int i = 0; i < 8; ++i) af[i] = *(const bf16x8*)(At + arow[i] + slk);
        #pragma unroll
        for (int j = 0; j < 2; ++j) bq[j] = *(const bf16x8*)(Bt + brow[j] + slk);
        SCHED0; BAR; LGKM0; SCHED0;
        __builtin_amdgcn_s_setprio(1);
        #pragma unroll
        for (int i = 0; i < 8; ++i)
            #pragma unroll
            for (int j = 0; j < 2; ++j)
                acc[i][j] = __builtin_amdgcn_mfma_f32_16x16x32_bf16(af[i], bq[j], acc[i][j], 0, 0, 0);
        __builtin_amdgcn_s_setprio(0);
    };

    // prologue: tile0 fully, then A(1). Order: B(0),A(0)h0,A(0)h1, A(1)h0,A(1)h1 = 10 loads.
    stageB(0); stageA(0, 0); stageA(1, 0); stageA(0, 1); stageA(1, 1);
    VMCNT4;    // retire tile0's 6 loads; A(1)'s 4 stay in flight
    SCHED0; BAR;

    for (int t = 0; t < 16; ++t) {
        const ushort_t* At = &Asm[(t % 3) * A_TILE];
        const ushort_t* Bt = &Bsm[(t & 1) * B_TILE];

        // ---- ph1 (ks0): reads, then issue B(t+1), A-h0(t+2) ----
        {
            bf16x8 af[8], bq[2];
            #pragma unroll
            for (int i = 0; i < 8; ++i) af[i] = *(const bf16x8*)(At + arow[i] + sl0);
            #pragma unroll
            for (int j = 0; j < 2; ++j) bq[j] = *(const bf16x8*)(Bt + brow[j] + sl0);
            if (t <= 14) stageB(t + 1);
            if (t <= 13) stageA(0, t + 2);
            SCHED0; BAR; LGKM0; SCHED0;
            __builtin_amdgcn_s_setprio(1);
            #pragma unroll
            for (int i = 0; i < 8; ++i)
                #pragma unroll
                for (int j = 0; j < 2; ++j)
                    acc[i][j] = __builtin_amdgcn_mfma_f32_16x16x32_bf16(af[i], bq[j], acc[i][j], 0, 0, 0);
            __builtin_amdgcn_s_setprio(0);
            SCHED0; BAR;
        }
        // ---- ph2 (ks1): reads, then issue A-h1(t+2); tile-boundary vmcnt ----
        {
            bf16x8 af[8], bq[2];
            #pragma unroll
            for (int i = 0; i < 8; ++i) af[i] = *(const bf16x8*)(At + arow[i] + sl1);
            #pragma unroll
            for (int j = 0; j < 2; ++j) bq[j] = *(const bf16x8*)(Bt + brow[j] + sl1);
            if (t <= 13) stageA(1, t + 2);
            SCHED0; BAR; LGKM0; SCHED0;
            __builtin_amdgcn_s_setprio(1);
            #pragma unroll
            for (int i = 0; i < 8; ++i)
                #pragma unroll
                for (int j = 0; j < 2; ++j)
                    acc[i][j] = __builtin_amdgcn_mfma_f32_16x16x32_bf16(af[i], bq[j], acc[i][j], 0, 0, 0);
            __builtin_amdgcn_s_setprio(0);
            if (t <= 13)      { VMCNT4; }   // retire {A,B}(t+1); A(t+2) stays in flight
            else if (t == 14) { VMCNT0; }   // tail: B(15) just issued, must drain
            SCHED0; BAR;
        }
    }
    (void)phase;

    // ---- epilogue: h = tanh(acc + dec), p += h * v; reduce over n ----
    float p[8][4] = {};
    #pragma unroll
    for (int j = 0; j < 2; ++j) {
        const int nl = wn * 32 + j * 16 + r16;    // C/D: col = lane&15 -> n
        const float dd = s_dec[nl];
        const float vv = s_v[nl];
        #pragma unroll
        for (int i = 0; i < 8; ++i) {
            #pragma unroll
            for (int r = 0; r < 4; ++r) {         // C/D: row = q*4+r -> m
                float x = acc[i][j][r] + dd;
                if (!(x > -8.f)) x = -8.f;        // NaN-proof clamp
                if (x > 8.f)     x = 8.f;
                float e2 = __expf(2.f * x);
                float h  = 1.f - 2.f * __builtin_amdgcn_rcpf(e2 + 1.f);
                p[i][r] += h * vv;
            }
        }
    }
    #pragma unroll
    for (int msk = 1; msk < 16; msk <<= 1) {
        #pragma unroll
        for (int i = 0; i < 8; ++i)
            #pragma unroll
            for (int r = 0; r < 4; ++r)
                p[i][r] += __shfl_xor(p[i][r], msk, 64);
    }
    if (r16 == 0) {
        #pragma unroll
        for (int i = 0; i < 8; ++i)
            #pragma unroll
            for (int r = 0; r < 4; ++r)
                s_sc[wn][wm * 128 + i * 16 + q * 4 + r] = p[i][r];
    }
    __syncthreads();
    if (tid < 256)
        partial[(size_t)n_block * M_TOT + m_base + tid] =
            s_sc[0][tid] + s_sc[1][tid] + s_sc[2][tid] + s_sc[3][tid];
}

// ---------------- fallback GEMM (fp32 in-kernel pack) if workspace too small ----------
__global__ __launch_bounds__(256) void fused_gemm_fp32_kernel(
    const float* __restrict__ enc,
    const float* __restrict__ Wa,
    const float* __restrict__ v,
    const float* __restrict__ dp,
    float* __restrict__ partial)
{
    __shared__ unsigned short As[128 * 32];
    __shared__ unsigned short Bs[128 * 32];
    __shared__ float s_dec[128];
    __shared__ float s_v[128];
    __shared__ float s_score[128];

    const int tid  = threadIdx.x;
    const int lane = tid & 63;
    const int wave = tid >> 6;
    const int wm   = wave >> 1;
    const int wn   = wave & 1;

    const int flat    = blockIdx.y * 8 + blockIdx.x;
    const int n_block = (flat >> 3) & 7;
    const int m_block = (flat & 7) | ((flat >> 6) << 3);
    const int b_idx   = m_block >> 4;

    if (tid < 128) {
        s_dec[tid] = dp[b_idx * 1024 + n_block * 128 + tid];
        s_v[tid]   = v[n_block * 128 + tid];
    }

    const int r0  = tid >> 2;
    const int kk  = (tid & 3) * 8;
    const int r16 = lane & 15;
    const int q   = lane >> 4;

    const float* A_base = enc + (size_t)m_block * 128 * D_DIM;
    const float* B_base = Wa + (size_t)n_block * 128 * WA_LD + D_DIM;

    floatx4 acc[4][4] = {};

    for (int k0 = 0; k0 < 1024; k0 += 32) {
        float4 a0l = *(const float4*)(A_base + (size_t)r0        * D_DIM + k0 + kk);
        float4 a0h = *(const float4*)(A_base + (size_t)r0        * D_DIM + k0 + kk + 4);
        float4 a1l = *(const float4*)(A_base + (size_t)(r0 + 64) * D_DIM + k0 + kk);
        float4 a1h = *(const float4*)(A_base + (size_t)(r0 + 64) * D_DIM + k0 + kk + 4);
        float4 b0l = *(const float4*)(B_base + (size_t)r0        * WA_LD + k0 + kk);
        float4 b0h = *(const float4*)(B_base + (size_t)r0        * WA_LD + k0 + kk + 4);
        float4 b1l = *(const float4*)(B_base + (size_t)(r0 + 64) * WA_LD + k0 + kk);
        float4 b1h = *(const float4*)(B_base + (size_t)(r0 + 64) * WA_LD + k0 + kk + 4);
        uint4 pa0 = { pack2(a0l.x, a0l.y), pack2(a0l.z, a0l.w), pack2(a0h.x, a0h.y), pack2(a0h.z, a0h.w) };
        uint4 pa1 = { pack2(a1l.x, a1l.y), pack2(a1l.z, a1l.w), pack2(a1h.x, a1h.y), pack2(a1h.z, a1h.w) };
        uint4 pb0 = { pack2(b0l.x, b0l.y), pack2(b0l.z, b0l.w), pack2(b0h.x, b0h.y), pack2(b0h.z, b0h.w) };
        uint4 pb1 = { pack2(b1l.x, b1l.y), pack2(b1l.z, b1l.w), pack2(b1h.x, b1h.y), pack2(b1h.z, b1h.w) };
        __syncthreads();
        *(uint4*)&As[r0        * 32 + kk] = pa0;
        *(uint4*)&As[(r0 + 64) * 32 + kk] = pa1;
        *(uint4*)&Bs[r0        * 32 + kk] = pb0;
        *(uint4*)&Bs[(r0 + 64) * 32 + kk] = pb1;
        __syncthreads();

        bf16x8 af[4], bfr[4];
        #pragma unroll
        for (int i = 0; i < 4; ++i)
            af[i] = *(const bf16x8*)&As[(wm * 64 + i * 16 + r16) * 32 + q * 8];
        #pragma unroll
        for (int j = 0; j < 4; ++j)
            bfr[j] = *(const bf16x8*)&Bs[(wn * 64 + j * 16 + r16) * 32 + q * 8];
        #pragma unroll
        for (int i = 0; i < 4; ++i)
            #pragma unroll
            for (int j = 0; j < 4; ++j)
                acc[i][j] = __builtin_amdgcn_mfma_f32_16x16x32_bf16(af[i], bfr[j], acc[i][j], 0, 0, 0);
    }

    float p[4][4] = {};
    #pragma unroll
    for (int j = 0; j < 4; ++j) {
        const int nl = wn * 64 + j * 16 + r16;
        const float dd = s_dec[nl];
        const float vv = s_v[nl];
        #pragma unroll
        for (int i = 0; i < 4; ++i) {
            #pragma unroll
            for (int r = 0; r < 4; ++r) {
                float x = acc[i][j][r] + dd;
                if (!(x > -8.f)) x = -8.f;
                if (x > 8.f)     x = 8.f;
                float e2 = __expf(2.f * x);
                float h  = 1.f - 2.f * __builtin_amdgcn_rcpf(e2 + 1.f);
                p[i][r] += h * vv;
            }
        }
    }
    #pragma unroll
    for (int msk = 1; msk < 16; msk <<= 1) {
        #pragma unroll
        for (int i = 0; i < 4; ++i)
            #pragma unroll
            for (int r = 0; r < 4; ++r)
                p[i][r] += __shfl_xor(p[i][r], msk, 64);
    }
    __syncthreads();
    if (wn == 0 && r16 == 0) {
        #pragma unroll
        for (int i = 0; i < 4; ++i)
            #pragma unroll
            for (int r = 0; r < 4; ++r)
                s_score[wm * 64 + i * 16 + q * 4 + r] = p[i][r];
    }
    __syncthreads();
    if (wn == 1 && r16 == 0) {
        #pragma unroll
        for (int i = 0; i < 4; ++i)
            #pragma unroll
            for (int r = 0; r < 4; ++r)
                s_score[wm * 64 + i * 16 + q * 4 + r] += p[i][r];
    }
    __syncthreads();
    if (tid < 128)
        partial[(size_t)n_block * M_TOT + m_block * 128 + tid] = s_score[tid];
}

// ---------------- kernel 3: softmax over s per batch row (1024 thr) ----------------
__global__ __launch_bounds__(1024) void softmax_kernel(
    const float* __restrict__ partial,   // [8][65536]
    float* __restrict__ out)             // [32][2048] f32
{
    const int b = blockIdx.x;
    const int tid = threadIdx.x;
    const int wv = tid >> 6;
    __shared__ float wred[16];

    float sc[2];
    float mx = -1e30f;
    #pragma unroll
    for (int ii = 0; ii < 2; ++ii) {
        const int s = tid + ii * 1024;
        float sum = 0.f;
        #pragma unroll
        for (int pp = 0; pp < 8; ++pp)
            sum += partial[(size_t)pp * M_TOT + b * S_DIM + s];
        sc[ii] = sum;
        mx = fmaxf(mx, sum);
    }
    #pragma unroll
    for (int msk = 1; msk < 64; msk <<= 1) mx = fmaxf(mx, __shfl_xor(mx, msk, 64));
    if ((tid & 63) == 0) wred[wv] = mx;
    __syncthreads();
    #pragma unroll
    for (int k = 0; k < 16; ++k) mx = fmaxf(mx, wred[k]);
    __syncthreads();

    float ex[2];
    float tot = 0.f;
    #pragma unroll
    for (int ii = 0; ii < 2; ++ii) { ex[ii] = __expf(sc[ii] - mx); tot += ex[ii]; }
    #pragma unroll
    for (int msk = 1; msk < 64; msk <<= 1) tot += __shfl_xor(tot, msk, 64);
    if ((tid & 63) == 0) wred[wv] = tot;
    __syncthreads();
    tot = 0.f;
    #pragma unroll
    for (int k = 0; k < 16; ++k) tot += wred[k];
    const float inv = 1.f / tot;
    #pragma unroll
    for (int ii = 0; ii < 2; ++ii)
        out[b * S_DIM + tid + ii * 1024] = ex[ii] * inv;
}

extern "C" void kernel_launch(void* const* d_in, const int* in_sizes, int n_in,
                              void* d_out, int out_size, void* d_ws, size_t ws_size,
                              hipStream_t stream) {
    (void)in_sizes; (void)n_in; (void)out_size;
    const float* dec = (const float*)d_in[0];
    const float* enc = (const float*)d_in[1];
    const float* Wa  = (const float*)d_in[2];
    const float* v   = (const float*)d_in[3];
    float* out = (float*)d_out;

    float* dp      = (float*)d_ws;        // 32*1024 floats   = 128 KB
    float* partial = dp + 32 * 1024;      // 8*65536 floats   = 2 MB

    const size_t NEED = (size_t)(32 * 1024 + 8 * 65536) * 4
                      + (size_t)67108864 * 2            // enc bf16
                      + (size_t)1048576 * 2;            // We bf16

    if (ws_size >= NEED) {
        ushort_t* encb = (ushort_t*)(partial + 8 * 65536);
        ushort_t* Web  = encb + 67108864;
        convertW_kernel<<<dim3(1024), 256, 0, stream>>>(Wa, Web);
        convert_enc_kernel<<<dim3(4096), 256, 0, stream>>>(enc, encb);
        decproj_kernel<<<dim3(256), 256, 0, stream>>>(dec, Wa, dp);
        gemm_bf16_kernel<<<dim3(8, 256), 512, 0, stream>>>(encb, Web, v, dp, partial);
    } else {
        decproj_kernel<<<dim3(256), 256, 0, stream>>>(dec, Wa, dp);
        fused_gemm_fp32_kernel<<<dim3(8, 512), 256, 0, stream>>>(enc, Wa, v, dp, partial);
    }
    softmax_kernel<<<32, 1024, 0, stream>>>(partial, out);
}